// Round 1
// 2383.210 us; speedup vs baseline: 6.5807x; 6.5807x over previous
//
#include <hip/hip_runtime.h>

// Qwen3 attention block, MI355X gfx950.
// Round 6: FULL MFMA PIPELINE. Bisection complete (round-5 passed, absmax
// 0.03125). Counters: naive_attn 4.95 ms (MfmaUtil 0, VALUBusy 67%) +
// naive Wq gemm 4.88 ms (MfmaUtil 0, 1.3e8 LDS bank conflicts) dominate.
// This round: all projections via gemm_nt (MFMA, validated in rounds 3-5),
// plus a new MFMA flash attention (swapped-QK^T, XOR-swizzled K tile,
// transposed+padded V tile, online softmax).
// ws (24 MiB + 4 KiB): [0,4K) control {flag, qwc[128], kwc[128]}
//   [4K,+4M) kq bf16 [2048][8][128] | [+4M,+8M) vb bf16 | [+8M,+24M) attnbuf bf16
// d_out (fp32): out [0,8388608) | k [8388608,10485760) | v [10485760,12582912)
//   (bf16 q scratch borrows out's first 16 MiB; overwritten by final gemm)

typedef __bf16 bf16;
typedef __bf16 bf16x8 __attribute__((ext_vector_type(8)));
typedef float  f32x4  __attribute__((ext_vector_type(4)));

#define MFMA16(a, b, c) __builtin_amdgcn_mfma_f32_16x16x32_bf16((a), (b), (c), 0, 0, 0)

// ---------------------------------------------------------------- dtype probe
__global__ __launch_bounds__(256) void detect_convert(
    const unsigned short* __restrict__ probe,   // Wq bits
    const void* __restrict__ qw_raw, const void* __restrict__ kw_raw,
    int* __restrict__ flag, bf16* __restrict__ qwc, bf16* __restrict__ kwc) {
    __shared__ int cnt;
    if (threadIdx.x == 0) cnt = 0;
    __syncthreads();
    int local = 0;
    for (int i = 0; i < 4; ++i) {
        const unsigned short w = probe[(threadIdx.x * 4 + i) * 2];
        const int e = (w >> 7) & 0xFF;
        if (e >= 90 && e <= 140) ++local;
    }
    atomicAdd(&cnt, local);
    __syncthreads();
    const bool isbf16 = cnt >= 700;
    if (threadIdx.x == 0) *flag = isbf16 ? 1 : 0;
    const int t = threadIdx.x;
    if (t < 128)
        qwc[t] = isbf16 ? ((const bf16*)qw_raw)[t] : (bf16)((const float*)qw_raw)[t];
    else
        kwc[t - 128] = isbf16 ? ((const bf16*)kw_raw)[t - 128] : (bf16)((const float*)kw_raw)[t - 128];
}

// ---------------------------------------------------------------- MFMA GEMM
// Round-3 core + optional fp32 output (Cf). C row-major; writes whichever of
// Cb (bf16) / Cf (fp32) is non-null, straight from the fp32 accumulator.
#define GBM 128
#define GBN 128
#define GBK 64
#define GLD 72

__global__ __launch_bounds__(256) void gemm_nt(const void* __restrict__ Av,
                                               const void* __restrict__ Bv,
                                               bf16* __restrict__ Cb,
                                               float* __restrict__ Cf,
                                               const int* __restrict__ flag,
                                               int aForceBf16,
                                               int M, int K,
                                               int ldb, int ldc, int col0) {
    __shared__ __align__(16) bf16 As[GBM * GLD];
    __shared__ __align__(16) bf16 Bs[GBN * GLD];
    const bool bBf16 = (*flag) != 0;
    const bool aBf16 = aForceBf16 || bBf16;
    const bf16*  Ab = (const bf16*)Av;
    const float* Af = (const float*)Av;
    const bf16*  Bb = (const bf16*)Bv;
    const float* Bf = (const float*)Bv;

    const int tid  = threadIdx.x;
    const int wave = tid >> 6;
    const int lane = tid & 63;
    const int l15  = lane & 15;
    const int quad = lane >> 4;
    const int m0 = blockIdx.y * GBM;
    const int n0 = blockIdx.x * GBN;
    const int wm = (wave >> 1) * 64;
    const int wn = (wave & 1) * 64;

    f32x4 acc[4][4];
    for (int i = 0; i < 4; ++i)
        for (int j = 0; j < 4; ++j) acc[i][j] = {0.f, 0.f, 0.f, 0.f};

    for (int k0 = 0; k0 < K; k0 += GBK) {
        for (int p = 0; p < 4; ++p) {
            const int c = p * 256 + tid;
            const int ar = c >> 3, ak = c & 7;
            const size_t aidx = (size_t)(m0 + ar) * K + k0 + ak * 8;
            bf16x8 avv;
            if (aBf16) {
                avv = *(const bf16x8*)&Ab[aidx];
            } else {
                const f32x4 a0 = *(const f32x4*)&Af[aidx];
                const f32x4 a1 = *(const f32x4*)&Af[aidx + 4];
                for (int e = 0; e < 4; ++e) { avv[e] = (bf16)a0[e]; avv[e + 4] = (bf16)a1[e]; }
            }
            *(bf16x8*)&As[ar * GLD + ak * 8] = avv;
            const int bk = c >> 4, bn = c & 15;
            const size_t bidx = (size_t)(k0 + bk) * ldb + n0 + bn * 8;
            bf16x8 bvv;
            if (bBf16) {
                bvv = *(const bf16x8*)&Bb[bidx];
            } else {
                const f32x4 b0 = *(const f32x4*)&Bf[bidx];
                const f32x4 b1 = *(const f32x4*)&Bf[bidx + 4];
                for (int e = 0; e < 4; ++e) { bvv[e] = (bf16)b0[e]; bvv[e + 4] = (bf16)b1[e]; }
            }
            for (int e = 0; e < 8; ++e) Bs[(bn * 8 + e) * GLD + bk] = bvv[e];
        }
        __syncthreads();
        for (int kk = 0; kk < GBK; kk += 32) {
            bf16x8 af[4], bfr[4];
            for (int i = 0; i < 4; ++i)
                af[i] = *(const bf16x8*)&As[(wm + i * 16 + l15) * GLD + kk + quad * 8];
            for (int j = 0; j < 4; ++j)
                bfr[j] = *(const bf16x8*)&Bs[(wn + j * 16 + l15) * GLD + kk + quad * 8];
            for (int i = 0; i < 4; ++i)
                for (int j = 0; j < 4; ++j)
                    acc[i][j] = MFMA16(af[i], bfr[j], acc[i][j]);
        }
        __syncthreads();
    }
    for (int i = 0; i < 4; ++i)
        for (int j = 0; j < 4; ++j)
            for (int r = 0; r < 4; ++r) {
                const int row = m0 + wm + i * 16 + quad * 4 + r;
                const int col = col0 + n0 + wn + j * 16 + l15;
                const float v = acc[i][j][r];
                if (Cb) Cb[(size_t)row * ldc + col] = (bf16)v;
                if (Cf) Cf[(size_t)row * ldc + col] = v;
            }
}

// ---------------------------------------------------------------- norm + rope
// One wave per (token, head); src is [T][H][128] bf16. Writes bf16 (dst_bf,
// may alias src) and/or fp32 (dst_f32).
__global__ __launch_bounds__(256) void norm_rope(const bf16* __restrict__ src,
                                                 bf16* __restrict__ dst_bf,
                                                 float* __restrict__ dst_f32,
                                                 const bf16* __restrict__ w,
                                                 const int* __restrict__ positions,
                                                 int H) {
    const int wid  = blockIdx.x * 4 + (threadIdx.x >> 6);
    const int lane = threadIdx.x & 63;
    const int token = wid / H, head = wid % H;
    const bf16* s = src + ((size_t)token * H + head) * 128;
    const float f0 = (float)s[lane], f1 = (float)s[lane + 64];
    float ss = f0 * f0 + f1 * f1;
    for (int off = 32; off >= 1; off >>= 1) ss += __shfl_xor(ss, off);
    const float inv_rms = rsqrtf(ss * (1.0f / 128.0f) + 1e-6f);
    const float n0 = f0 * inv_rms * (float)w[lane];
    const float n1 = f1 * inv_rms * (float)w[lane + 64];
    const float pos = (float)positions[token];
    const float inv_ts = expf((float)lane * (-13.815510557964274f / 64.0f));
    const float ang = pos * inv_ts;
    const float sn = sinf(ang), cs = cosf(ang);
    const float o0 = n0 * cs - n1 * sn;
    const float o1 = n1 * cs + n0 * sn;
    const size_t base = ((size_t)token * H + head) * 128;
    if (dst_bf)  { dst_bf[base + lane] = (bf16)o0;  dst_bf[base + lane + 64] = (bf16)o1; }
    if (dst_f32) { dst_f32[base + lane] = o0;       dst_f32[base + lane + 64] = o1; }
}

// ---------------------------------------------------------------- MFMA flash attention
// Grid (32 heads, 32 q-tiles). Block = 4 waves; wave w owns q rows
// [qt*64 + w*16, +16) of head h. KV tiles of 32 keys staged in LDS.
//  - S^T = mfma(A=K_tile, B=Q^T): D row = key (quad*4+reg), col = q (l15)
//    => row-softmax reduce is shfl_xor(16)+shfl_xor(32) across quads.
//  - K tile [32][128] XOR-swizzled (byte ^= (row&7)<<4): conflict-free
//    ds_read_b128 A-fragments (G4 recipe).
//  - V staged transposed Vt[d][key], key-stride padded 32->40 so PV
//    B-fragments are aligned ds_read_b128 at ~2-way banks.
//  - P round-trips through a per-wave padded LDS tile to convert D-layout
//    (q=l15 cols) into A-layout (q=l15 rows, key=quad*8+i).
__global__ __launch_bounds__(256) void flash_attn(const bf16* __restrict__ Q,
                                                  const bf16* __restrict__ Kg,
                                                  const bf16* __restrict__ Vg,
                                                  bf16* __restrict__ Og) {
    __shared__ __align__(16) bf16 Ks[32 * 128];     // 8 KiB, swizzled
    __shared__ __align__(16) bf16 Vt[128 * 40];     // 10 KiB, V^T padded
    __shared__ __align__(16) bf16 Ps[4][16 * 40];   // 5 KiB, per-wave P

    const int h    = blockIdx.x;            // 0..31
    const int qt   = 31 - blockIdx.y;       // heavy (long-loop) tiles first
    const int kvh  = h >> 2;
    const int tid  = threadIdx.x;
    const int wave = tid >> 6;
    const int lane = tid & 63;
    const int l15  = lane & 15;
    const int quad = lane >> 4;
    const int q0   = qt * 64;
    const int qw0  = q0 + wave * 16;
    const int myq  = qw0 + l15;
    const float scale = 0.08838834764831845f;  // 1/sqrt(128)

    // Q B-fragments: lane holds Q[row qw0+l15][k = kc*32 + quad*8 + i]
    bf16x8 qf[4];
    {
        const bf16* qrow = Q + ((size_t)myq * 32 + h) * 128;
#pragma unroll
        for (int kc = 0; kc < 4; ++kc)
            qf[kc] = *(const bf16x8*)&qrow[kc * 32 + quad * 8];
    }

    f32x4 oacc[8];
#pragma unroll
    for (int i = 0; i < 8; ++i) oacc[i] = {0.f, 0.f, 0.f, 0.f};
    float m_run = -1e30f, l_run = 0.f;

    // staging assignments (per thread, whole block cooperates)
    const int ksr  = tid & 31;        // K: row, col-chunks (tid>>5) and +8
    const int kscb = tid >> 5;
    const int vr0  = (tid & 15) * 2;  // V: row pair
    const int vcb  = tid >> 4;        // V: col chunk 0..15

    char* kbytes = (char*)Ks;
    char* vbytes = (char*)Vt;
    char* pbytes = (char*)&Ps[wave][0];

    const int ntiles = (q0 + 64) >> 5;   // keys 0 .. q0+63
    for (int kt = 0; kt < ntiles; ++kt) {
        const int kb = kt * 32;
        // ---- stage K tile (XOR-swizzled) ----
        {
            const bf16* src = Kg + ((size_t)(kb + ksr) * 8 + kvh) * 128;
            const bf16x8 v0 = *(const bf16x8*)&src[kscb * 8];
            const bf16x8 v1 = *(const bf16x8*)&src[(kscb + 8) * 8];
            const int b0 = (ksr * 256 + kscb * 16) ^ ((ksr & 7) << 4);
            const int b1 = (ksr * 256 + (kscb + 8) * 16) ^ ((ksr & 7) << 4);
            *(bf16x8*)(kbytes + b0) = v0;
            *(bf16x8*)(kbytes + b1) = v1;
        }
        // ---- stage V^T (row-pair packed b32 scatter) ----
        {
            const bf16* s0 = Vg + ((size_t)(kb + vr0) * 8 + kvh) * 128 + vcb * 8;
            const bf16x8 a = *(const bf16x8*)s0;
            const bf16x8 b = *(const bf16x8*)(s0 + 1024);  // next key row
#pragma unroll
            for (int e = 0; e < 8; ++e) {
                union { bf16 hh[2]; unsigned int u; } pk;
                pk.hh[0] = a[e]; pk.hh[1] = b[e];
                *(unsigned int*)(vbytes + (vcb * 8 + e) * 80 + vr0 * 2) = pk.u;
            }
        }
        __syncthreads();

        // ---- S^T = K @ Q^T over 32 keys x 16 q rows ----
        f32x4 sacc[2];
        sacc[0] = {0.f, 0.f, 0.f, 0.f};
        sacc[1] = {0.f, 0.f, 0.f, 0.f};
#pragma unroll
        for (int st = 0; st < 2; ++st) {
            const int row = st * 16 + l15;
#pragma unroll
            for (int kc = 0; kc < 4; ++kc) {
                const int bofs = (row * 256 + kc * 64 + quad * 16) ^ ((row & 7) << 4);
                const bf16x8 kf = *(const bf16x8*)(kbytes + bofs);
                sacc[st] = MFMA16(kf, qf[kc], sacc[st]);
            }
        }

        // ---- online softmax (per q = myq; stats replicated across quads) ----
        float sv[8];
        float pm = -1e30f;
#pragma unroll
        for (int st = 0; st < 2; ++st)
#pragma unroll
            for (int r = 0; r < 4; ++r) {
                const int key = kb + st * 16 + quad * 4 + r;
                float s = sacc[st][r] * scale;
                if (key > myq) s = -1e30f;        // causal mask
                sv[st * 4 + r] = s;
                pm = fmaxf(pm, s);
            }
        pm = fmaxf(pm, __shfl_xor(pm, 16));
        pm = fmaxf(pm, __shfl_xor(pm, 32));
        const float m_new = fmaxf(m_run, pm);
        const float corr = __expf(m_run - m_new);
        float ps = 0.f;
        bf16 pb[8];
#pragma unroll
        for (int i = 0; i < 8; ++i) {
            const float p = __expf(sv[i] - m_new);
            ps += p;
            pb[i] = (bf16)p;
        }
        ps += __shfl_xor(ps, 16);
        ps += __shfl_xor(ps, 32);
        l_run = l_run * corr + ps;
        m_run = m_new;

        // ---- P -> LDS (D-layout scatter; wave-local, DS ops in-order) ----
#pragma unroll
        for (int st = 0; st < 2; ++st)
#pragma unroll
            for (int r = 0; r < 4; ++r)
                *(bf16*)(pbytes + l15 * 80 + (st * 16 + quad * 4 + r) * 2) = pb[st * 4 + r];

        // ---- rescale O by corr (O rows are quad*4+r; corr lives at lane q) ----
        float corrq[4];
#pragma unroll
        for (int r = 0; r < 4; ++r) corrq[r] = __shfl(corr, quad * 4 + r);
#pragma unroll
        for (int nt = 0; nt < 8; ++nt)
#pragma unroll
            for (int r = 0; r < 4; ++r) oacc[nt][r] *= corrq[r];

        // ---- PV: O += P @ V ----
        const bf16x8 pf = *(const bf16x8*)(pbytes + l15 * 80 + quad * 16);
#pragma unroll
        for (int nt = 0; nt < 8; ++nt) {
            const bf16x8 vf = *(const bf16x8*)(vbytes + (nt * 16 + l15) * 80 + quad * 16);
            oacc[nt] = MFMA16(pf, vf, oacc[nt]);
        }
        __syncthreads();
    }

    // ---- epilogue: divide by row sum, write O[q][h][d] bf16 ----
    const float rinv = 1.0f / l_run;
    float linv[4];
#pragma unroll
    for (int r = 0; r < 4; ++r) linv[r] = __shfl(rinv, quad * 4 + r);
#pragma unroll
    for (int nt = 0; nt < 8; ++nt)
#pragma unroll
        for (int r = 0; r < 4; ++r) {
            const int row = qw0 + quad * 4 + r;
            Og[((size_t)row * 32 + h) * 128 + nt * 16 + l15] = (bf16)(oacc[nt][r] * linv[r]);
        }
}

// ---------------------------------------------------------------- launch
extern "C" void kernel_launch(void* const* d_in, const int* in_sizes, int n_in,
                              void* d_out, int out_size, void* d_ws, size_t ws_size,
                              hipStream_t stream) {
    const void* x  = d_in[0];   // [2048][4096]  fp32 (auto-detected)
    const void* Wq = d_in[1];   // [4096][4096]
    const void* Wk = d_in[2];   // [4096][1024]
    const void* Wv = d_in[3];   // [4096][1024]
    const void* Wo = d_in[4];   // [4096][4096]
    const void* qw = d_in[5];   // [128]
    const void* kw = d_in[6];   // [128]
    const int* positions = (const int*)d_in[8];

    char* ws = (char*)d_ws;
    int*  flag    = (int*)ws;
    bf16* qwc     = (bf16*)(ws + 64);
    bf16* kwc     = (bf16*)(ws + 64 + 256);
    bf16* kq      = (bf16*)(ws + 4096);                 // [2048][8][128] bf16
    bf16* vb      = (bf16*)(ws + 4096 + 4194304);       // [2048][8][128] bf16
    bf16* attnbuf = (bf16*)(ws + 4096 + 8388608);       // [2048][32][128] bf16

    float* outf = (float*)d_out;           // [2048][4096] fp32
    float* Kof  = outf + 8388608;          // [2048][8][128] fp32
    float* Vof  = outf + 10485760;         // [2048][8][128] fp32
    bf16*  qb   = (bf16*)d_out;            // bf16 q scratch in out's first 16 MiB

    detect_convert<<<1, 256, 0, stream>>>((const unsigned short*)Wq, qw, kw, flag, qwc, kwc);

    // Projections (all MFMA). V writes bf16 (attn input) + fp32 (output 2).
    gemm_nt<<<dim3(32, 16), 256, 0, stream>>>(x, Wq, qb, nullptr, flag, 0, 2048, 4096, 4096, 4096, 0);
    gemm_nt<<<dim3(8, 16),  256, 0, stream>>>(x, Wk, kq, nullptr, flag, 0, 2048, 4096, 1024, 1024, 0);
    gemm_nt<<<dim3(8, 16),  256, 0, stream>>>(x, Wv, vb, Vof,    flag, 0, 2048, 4096, 1024, 1024, 0);

    // Norm+RoPE. q in-place bf16; k in-place bf16 (attn input) + fp32 (output 1).
    norm_rope<<<16384, 256, 0, stream>>>(qb, qb, nullptr, qwc, positions, 32);
    norm_rope<<<4096, 256, 0, stream>>>(kq, kq, Kof, kwc, positions, 8);

    // Flash attention (MFMA) -> attnbuf bf16 [2048][32][128].
    flash_attn<<<dim3(32, 32), 256, 0, stream>>>(qb, kq, vb, attnbuf);

    // Output projection -> fp32 out (overwrites qb scratch after last use).
    gemm_nt<<<dim3(32, 16), 256, 0, stream>>>(attnbuf, Wo, nullptr, outf, flag, 1, 2048, 4096, 4096, 4096, 0);
}

// Round 3
// 901.717 us; speedup vs baseline: 17.3927x; 2.6430x over previous
//
#include <hip/hip_runtime.h>

// Qwen3 attention block, MI355X gfx950.
// Round 8: RESUBMIT of round 7 (container failed twice -- infra, not kernel:
// code audit found no OOB/aliasing/capture hazard; round-1 timing already
// showed fabric distress with 1378s npz pushes). Kernel unchanged.
// Round 7: LDS-CONFLICT FIX. Round-6 counters: gemm_nt 715us/dispatch with
// SQ_LDS_BANK_CONFLICT saturated at 2^27, MfmaUtil 3.8%, VALUBusy 2.8% ->
// LDS-pipe-bound on the Bs transpose-scatter (scalar ds_write_b16, bn-stride
// 1152B = 0 mod 128 -> 32-way conflict). WRITE_SIZE 2.1GB is a counter
// artifact (no physical source; real read BW 280GB/s). This round:
//  - B staged via column-chunk loads (8 coalesced loads/lane) + single
//    ds_write_b128 at n*GLD (stride 144B = 9x16B, conflict-free).
//  - x pre-converted to bf16 once (convert_x); A-path always bf16.
//  - Wk+Wv merged into one launch (grid 256, was 2x128 = half CUs idle).
//  - XCD-chunked swizzle on gemms; flash work map head-major per XCD.
// ws (24 MiB + 4 KiB): [0,4K) control {flag, qwc[128], kwc[128]}
//   [4K,+4M) kq bf16 | [+4M,+8M) vb bf16 | [+8M,+24M) xb bf16 then attnbuf
//   (xb [2048][4096] bf16 dead before flash_attn writes attnbuf over it)
// d_out (fp32): out [0,8388608) | k [8388608,10485760) | v [10485760,12582912)
//   (bf16 q scratch borrows out's first 16 MiB; overwritten by final gemm)

typedef __bf16 bf16;
typedef __bf16 bf16x8 __attribute__((ext_vector_type(8)));
typedef float  f32x4  __attribute__((ext_vector_type(4)));

#define MFMA16(a, b, c) __builtin_amdgcn_mfma_f32_16x16x32_bf16((a), (b), (c), 0, 0, 0)

// ---------------------------------------------------------------- dtype probe
__global__ __launch_bounds__(256) void detect_convert(
    const unsigned short* __restrict__ probe,   // Wq bits
    const void* __restrict__ qw_raw, const void* __restrict__ kw_raw,
    int* __restrict__ flag, bf16* __restrict__ qwc, bf16* __restrict__ kwc) {
    __shared__ int cnt;
    if (threadIdx.x == 0) cnt = 0;
    __syncthreads();
    int local = 0;
    for (int i = 0; i < 4; ++i) {
        const unsigned short w = probe[(threadIdx.x * 4 + i) * 2];
        const int e = (w >> 7) & 0xFF;
        if (e >= 90 && e <= 140) ++local;
    }
    atomicAdd(&cnt, local);
    __syncthreads();
    const bool isbf16 = cnt >= 700;
    if (threadIdx.x == 0) *flag = isbf16 ? 1 : 0;
    const int t = threadIdx.x;
    if (t < 128)
        qwc[t] = isbf16 ? ((const bf16*)qw_raw)[t] : (bf16)((const float*)qw_raw)[t];
    else
        kwc[t - 128] = isbf16 ? ((const bf16*)kw_raw)[t - 128] : (bf16)((const float*)kw_raw)[t - 128];
}

// ---------------------------------------------------------------- x -> bf16
__global__ __launch_bounds__(256) void convert_x(const void* __restrict__ xv,
                                                 bf16* __restrict__ xb,
                                                 const int* __restrict__ flag) {
    const size_t i8 = ((size_t)blockIdx.x * 256 + threadIdx.x) * 8;
    if (*flag) {
        *(bf16x8*)&xb[i8] = *(const bf16x8*)&((const bf16*)xv)[i8];
    } else {
        const f32x4 a = *(const f32x4*)&((const float*)xv)[i8];
        const f32x4 b = *(const f32x4*)&((const float*)xv)[i8 + 4];
        bf16x8 o;
#pragma unroll
        for (int e = 0; e < 4; ++e) { o[e] = (bf16)a[e]; o[e + 4] = (bf16)b[e]; }
        *(bf16x8*)&xb[i8] = o;
    }
}

// ---------------------------------------------------------------- MFMA GEMM
// A bf16 [M][K] row-major. B (fp32 or bf16 via flag) [K][N] row-major.
// Two B/C sets: blocks bx < nsplit use set 1, else set 2 (merged launches).
// Staging: A row-chunks (b128 global + b128 LDS, conflict-free);
// B column-chunks (8 coalesced per-lane loads, single b128 LDS write at
// n*GLD -- 144B stride = 9x16B, conflict-free). MFMA core unchanged.
#define GBM 128
#define GBN 128
#define GBK 64
#define GLD 72

__global__ __launch_bounds__(256) void gemm_nt(
    const bf16* __restrict__ A,
    const void* __restrict__ B1v, const void* __restrict__ B2v,
    bf16* __restrict__ Cb1, float* __restrict__ Cf1,
    bf16* __restrict__ Cb2, float* __restrict__ Cf2,
    const int* __restrict__ flag,
    int K, int ldb, int ldc1, int ldc2, int nsplit) {
    __shared__ __align__(16) bf16 As[GBM * GLD];
    __shared__ __align__(16) bf16 Bs[GBN * GLD];

    // XCD-chunked swizzle (nwg % 8 == 0 for all launches)
    int id = blockIdx.y * gridDim.x + blockIdx.x;
    const int nwg = gridDim.x * gridDim.y;
    id = (id & 7) * (nwg >> 3) + (id >> 3);
    const int bx = id % (int)gridDim.x;
    const int by = id / (int)gridDim.x;

    const void* Bv;
    bf16* Cb;
    float* Cf;
    int n0, ldc;
    if (bx < nsplit) { Bv = B1v; Cb = Cb1; Cf = Cf1; n0 = bx * GBN; ldc = ldc1; }
    else             { Bv = B2v; Cb = Cb2; Cf = Cf2; n0 = (bx - nsplit) * GBN; ldc = ldc2; }
    const int m0 = by * GBM;

    const bool bBf16 = (*flag) != 0;
    const bf16*  Bb = (const bf16*)Bv;
    const float* Bf = (const float*)Bv;

    const int tid  = threadIdx.x;
    const int wave = tid >> 6;
    const int lane = tid & 63;
    const int l15  = lane & 15;
    const int quad = lane >> 4;
    const int wm = (wave >> 1) * 64;
    const int wn = (wave & 1) * 64;

    f32x4 acc[4][4];
#pragma unroll
    for (int i = 0; i < 4; ++i)
#pragma unroll
        for (int j = 0; j < 4; ++j) acc[i][j] = {0.f, 0.f, 0.f, 0.f};

    for (int k0 = 0; k0 < K; k0 += GBK) {
        // ---- A: row chunks, b128 in / b128 out (conflict-free) ----
#pragma unroll
        for (int p = 0; p < 4; ++p) {
            const int c = p * 256 + tid;
            const int ar = c >> 3, ak = c & 7;
            const bf16x8 av = *(const bf16x8*)&A[(size_t)(m0 + ar) * K + k0 + ak * 8];
            *(bf16x8*)&As[ar * GLD + ak * 8] = av;
        }
        // ---- B: column chunks -> registers -> single b128 LDS write ----
#pragma unroll
        for (int p = 0; p < 4; ++p) {
            const int w16 = wave * 4 + p;       // 0..15
            const int nh = w16 & 1, kc = w16 >> 1;
            const int n = nh * 64 + lane;       // 0..127
            bf16x8 bv;
            if (bBf16) {
#pragma unroll
                for (int e = 0; e < 8; ++e)
                    bv[e] = Bb[(size_t)(k0 + kc * 8 + e) * ldb + n0 + n];
            } else {
#pragma unroll
                for (int e = 0; e < 8; ++e)
                    bv[e] = (bf16)Bf[(size_t)(k0 + kc * 8 + e) * ldb + n0 + n];
            }
            *(bf16x8*)&Bs[n * GLD + kc * 8] = bv;
        }
        __syncthreads();
        for (int kk = 0; kk < GBK; kk += 32) {
            bf16x8 af[4], bfr[4];
#pragma unroll
            for (int i = 0; i < 4; ++i)
                af[i] = *(const bf16x8*)&As[(wm + i * 16 + l15) * GLD + kk + quad * 8];
#pragma unroll
            for (int j = 0; j < 4; ++j)
                bfr[j] = *(const bf16x8*)&Bs[(wn + j * 16 + l15) * GLD + kk + quad * 8];
#pragma unroll
            for (int i = 0; i < 4; ++i)
#pragma unroll
                for (int j = 0; j < 4; ++j)
                    acc[i][j] = MFMA16(af[i], bfr[j], acc[i][j]);
        }
        __syncthreads();
    }
#pragma unroll
    for (int i = 0; i < 4; ++i)
#pragma unroll
        for (int j = 0; j < 4; ++j)
#pragma unroll
            for (int r = 0; r < 4; ++r) {
                const int row = m0 + wm + i * 16 + quad * 4 + r;
                const int col = n0 + wn + j * 16 + l15;
                const float v = acc[i][j][r];
                if (Cb) Cb[(size_t)row * ldc + col] = (bf16)v;
                if (Cf) Cf[(size_t)row * ldc + col] = v;
            }
}

// ---------------------------------------------------------------- norm + rope
__global__ __launch_bounds__(256) void norm_rope(const bf16* __restrict__ src,
                                                 bf16* __restrict__ dst_bf,
                                                 float* __restrict__ dst_f32,
                                                 const bf16* __restrict__ w,
                                                 const int* __restrict__ positions,
                                                 int H) {
    const int wid  = blockIdx.x * 4 + (threadIdx.x >> 6);
    const int lane = threadIdx.x & 63;
    const int token = wid / H, head = wid % H;
    const bf16* s = src + ((size_t)token * H + head) * 128;
    const float f0 = (float)s[lane], f1 = (float)s[lane + 64];
    float ss = f0 * f0 + f1 * f1;
    for (int off = 32; off >= 1; off >>= 1) ss += __shfl_xor(ss, off);
    const float inv_rms = rsqrtf(ss * (1.0f / 128.0f) + 1e-6f);
    const float n0 = f0 * inv_rms * (float)w[lane];
    const float n1 = f1 * inv_rms * (float)w[lane + 64];
    const float pos = (float)positions[token];
    const float inv_ts = expf((float)lane * (-13.815510557964274f / 64.0f));
    const float ang = pos * inv_ts;
    const float sn = sinf(ang), cs = cosf(ang);
    const float o0 = n0 * cs - n1 * sn;
    const float o1 = n1 * cs + n0 * sn;
    const size_t base = ((size_t)token * H + head) * 128;
    if (dst_bf)  { dst_bf[base + lane] = (bf16)o0;  dst_bf[base + lane + 64] = (bf16)o1; }
    if (dst_f32) { dst_f32[base + lane] = o0;       dst_f32[base + lane + 64] = o1; }
}

// ---------------------------------------------------------------- MFMA flash attention
// 1024 blocks; work id chunked so each XCD handles 4 consecutive heads
// (one KV head, ~1MB, resident in its private L2). Block = 4 waves; wave w
// owns q rows [qt*64 + w*16, +16) of head h. KV tiles of 32 keys in LDS.
__global__ __launch_bounds__(256) void flash_attn(const bf16* __restrict__ Q,
                                                  const bf16* __restrict__ Kg,
                                                  const bf16* __restrict__ Vg,
                                                  bf16* __restrict__ Og) {
    __shared__ __align__(16) bf16 Ks[32 * 128];     // 8 KiB, swizzled
    __shared__ __align__(16) bf16 Vt[128 * 40];     // 10 KiB, V^T padded
    __shared__ __align__(16) bf16 Ps[4][16 * 40];   // 5 KiB, per-wave P

    int id = blockIdx.y * 32 + blockIdx.x;
    id = (id & 7) * 128 + (id >> 3);        // XCD-chunked
    const int h  = id >> 5;                 // head-major within chunk
    const int qt = 31 - (id & 31);          // heavy (long-loop) tiles first
    const int kvh  = h >> 2;
    const int tid  = threadIdx.x;
    const int wave = tid >> 6;
    const int lane = tid & 63;
    const int l15  = lane & 15;
    const int quad = lane >> 4;
    const int q0   = qt * 64;
    const int qw0  = q0 + wave * 16;
    const int myq  = qw0 + l15;
    const float scale = 0.08838834764831845f;  // 1/sqrt(128)

    bf16x8 qf[4];
    {
        const bf16* qrow = Q + ((size_t)myq * 32 + h) * 128;
#pragma unroll
        for (int kc = 0; kc < 4; ++kc)
            qf[kc] = *(const bf16x8*)&qrow[kc * 32 + quad * 8];
    }

    f32x4 oacc[8];
#pragma unroll
    for (int i = 0; i < 8; ++i) oacc[i] = {0.f, 0.f, 0.f, 0.f};
    float m_run = -1e30f, l_run = 0.f;

    const int ksr  = tid & 31;
    const int kscb = tid >> 5;
    const int vr0  = (tid & 15) * 2;
    const int vcb  = tid >> 4;

    char* kbytes = (char*)Ks;
    char* vbytes = (char*)Vt;
    char* pbytes = (char*)&Ps[wave][0];

    const int ntiles = (q0 + 64) >> 5;
    for (int kt = 0; kt < ntiles; ++kt) {
        const int kb = kt * 32;
        {
            const bf16* src = Kg + ((size_t)(kb + ksr) * 8 + kvh) * 128;
            const bf16x8 v0 = *(const bf16x8*)&src[kscb * 8];
            const bf16x8 v1 = *(const bf16x8*)&src[(kscb + 8) * 8];
            const int b0 = (ksr * 256 + kscb * 16) ^ ((ksr & 7) << 4);
            const int b1 = (ksr * 256 + (kscb + 8) * 16) ^ ((ksr & 7) << 4);
            *(bf16x8*)(kbytes + b0) = v0;
            *(bf16x8*)(kbytes + b1) = v1;
        }
        {
            const bf16* s0 = Vg + ((size_t)(kb + vr0) * 8 + kvh) * 128 + vcb * 8;
            const bf16x8 a = *(const bf16x8*)s0;
            const bf16x8 b = *(const bf16x8*)(s0 + 1024);
#pragma unroll
            for (int e = 0; e < 8; ++e) {
                union { bf16 hh[2]; unsigned int u; } pk;
                pk.hh[0] = a[e]; pk.hh[1] = b[e];
                *(unsigned int*)(vbytes + (vcb * 8 + e) * 80 + vr0 * 2) = pk.u;
            }
        }
        __syncthreads();

        f32x4 sacc[2];
        sacc[0] = {0.f, 0.f, 0.f, 0.f};
        sacc[1] = {0.f, 0.f, 0.f, 0.f};
#pragma unroll
        for (int st = 0; st < 2; ++st) {
            const int row = st * 16 + l15;
#pragma unroll
            for (int kc = 0; kc < 4; ++kc) {
                const int bofs = (row * 256 + kc * 64 + quad * 16) ^ ((row & 7) << 4);
                const bf16x8 kf = *(const bf16x8*)(kbytes + bofs);
                sacc[st] = MFMA16(kf, qf[kc], sacc[st]);
            }
        }

        float sv[8];
        float pm = -1e30f;
#pragma unroll
        for (int st = 0; st < 2; ++st)
#pragma unroll
            for (int r = 0; r < 4; ++r) {
                const int key = kb + st * 16 + quad * 4 + r;
                float s = sacc[st][r] * scale;
                if (key > myq) s = -1e30f;
                sv[st * 4 + r] = s;
                pm = fmaxf(pm, s);
            }
        pm = fmaxf(pm, __shfl_xor(pm, 16));
        pm = fmaxf(pm, __shfl_xor(pm, 32));
        const float m_new = fmaxf(m_run, pm);
        const float corr = __expf(m_run - m_new);
        float ps = 0.f;
        bf16 pb[8];
#pragma unroll
        for (int i = 0; i < 8; ++i) {
            const float p = __expf(sv[i] - m_new);
            ps += p;
            pb[i] = (bf16)p;
        }
        ps += __shfl_xor(ps, 16);
        ps += __shfl_xor(ps, 32);
        l_run = l_run * corr + ps;
        m_run = m_new;

#pragma unroll
        for (int st = 0; st < 2; ++st)
#pragma unroll
            for (int r = 0; r < 4; ++r)
                *(bf16*)(pbytes + l15 * 80 + (st * 16 + quad * 4 + r) * 2) = pb[st * 4 + r];

        float corrq[4];
#pragma unroll
        for (int r = 0; r < 4; ++r) corrq[r] = __shfl(corr, quad * 4 + r);
#pragma unroll
        for (int nt = 0; nt < 8; ++nt)
#pragma unroll
            for (int r = 0; r < 4; ++r) oacc[nt][r] *= corrq[r];

        const bf16x8 pf = *(const bf16x8*)(pbytes + l15 * 80 + quad * 16);
#pragma unroll
        for (int nt = 0; nt < 8; ++nt) {
            const bf16x8 vf = *(const bf16x8*)(vbytes + (nt * 16 + l15) * 80 + quad * 16);
            oacc[nt] = MFMA16(pf, vf, oacc[nt]);
        }
        __syncthreads();
    }

    const float rinv = 1.0f / l_run;
    float linv[4];
#pragma unroll
    for (int r = 0; r < 4; ++r) linv[r] = __shfl(rinv, quad * 4 + r);
#pragma unroll
    for (int nt = 0; nt < 8; ++nt)
#pragma unroll
        for (int r = 0; r < 4; ++r) {
            const int row = qw0 + quad * 4 + r;
            Og[((size_t)row * 32 + h) * 128 + nt * 16 + l15] = (bf16)(oacc[nt][r] * linv[r]);
        }
}

// ---------------------------------------------------------------- launch
extern "C" void kernel_launch(void* const* d_in, const int* in_sizes, int n_in,
                              void* d_out, int out_size, void* d_ws, size_t ws_size,
                              hipStream_t stream) {
    const void* x  = d_in[0];   // [2048][4096]  fp32 or bf16 (auto-detected)
    const void* Wq = d_in[1];   // [4096][4096]
    const void* Wk = d_in[2];   // [4096][1024]
    const void* Wv = d_in[3];   // [4096][1024]
    const void* Wo = d_in[4];   // [4096][4096]
    const void* qw = d_in[5];   // [128]
    const void* kw = d_in[6];   // [128]
    const int* positions = (const int*)d_in[8];

    char* ws = (char*)d_ws;
    int*  flag    = (int*)ws;
    bf16* qwc     = (bf16*)(ws + 64);
    bf16* kwc     = (bf16*)(ws + 64 + 256);
    bf16* kq      = (bf16*)(ws + 4096);                 // [2048][8][128] bf16
    bf16* vb      = (bf16*)(ws + 4096 + 4194304);       // [2048][8][128] bf16
    bf16* xb      = (bf16*)(ws + 4096 + 8388608);       // [2048][4096] bf16 (pre-flash)
    bf16* attnbuf = (bf16*)(ws + 4096 + 8388608);       // [2048][32][128] bf16 (post-flash)

    float* outf = (float*)d_out;           // [2048][4096] fp32
    float* Kof  = outf + 8388608;          // [2048][8][128] fp32
    float* Vof  = outf + 10485760;         // [2048][8][128] fp32
    bf16*  qb   = (bf16*)d_out;            // bf16 q scratch in out's first 16 MiB

    detect_convert<<<1, 256, 0, stream>>>((const unsigned short*)Wq, qw, kw, flag, qwc, kwc);
    convert_x<<<4096, 256, 0, stream>>>(x, xb, flag);

    // Projections (all MFMA, A = xb bf16). Wq alone; Wk+Wv merged (nsplit=8).
    gemm_nt<<<dim3(32, 16), 256, 0, stream>>>(xb, Wq, nullptr, qb, nullptr, nullptr, nullptr,
                                              flag, 4096, 4096, 4096, 0, 32);
    gemm_nt<<<dim3(16, 16), 256, 0, stream>>>(xb, Wk, Wv, kq, nullptr, vb, Vof,
                                              flag, 4096, 1024, 1024, 1024, 8);

    // Norm+RoPE. q in-place bf16; k in-place bf16 (attn input) + fp32 (output 1).
    norm_rope<<<16384, 256, 0, stream>>>(qb, qb, nullptr, qwc, positions, 32);
    norm_rope<<<4096, 256, 0, stream>>>(kq, kq, Kof, kwc, positions, 8);

    // Flash attention (MFMA) -> attnbuf bf16 [2048][32][128] (overwrites xb).
    flash_attn<<<dim3(32, 32), 256, 0, stream>>>(qb, kq, vb, attnbuf);

    // Output projection -> fp32 out (overwrites qb scratch after last use).
    gemm_nt<<<dim3(32, 16), 256, 0, stream>>>(attnbuf, Wo, nullptr, nullptr, outf, nullptr, nullptr,
                                              flag, 4096, 4096, 4096, 0, 32);
}

// Round 4
// 697.674 us; speedup vs baseline: 22.4794x; 1.2925x over previous
//
#include <hip/hip_runtime.h>

// Qwen3 attention block, MI355X gfx950.
// Round 9: 2-PHASE PIPELINED GEMM. Round-8 counters: gemm_nt 205us with
// MfmaUtil 13%, VALUBusy 13%, HBM 18%, Occupancy 22% -- nothing saturated =
// latency-bound serial stage->barrier->MFMA->barrier loop (2 blocks/CU grid
// cap, 1 block/CU for the KV launch). This round:
//  - gemm_nt: double-buffered LDS (2x36KB), issue loads for t+1 BEFORE
//    computing t, ds_write after, ONE barrier per K-step (T3-minimum).
//  - Wq+Wk+Wv merged into a single 768-block launch (3-way split) -- fixes
//    the 1-block/CU starvation of the old KV launch.
//  - flash_attn / norm_rope / convert_x unchanged (validated round 8).
// ws (24 MiB + 4 KiB): [0,4K) control {flag, qwc[128], kwc[128]}
//   [4K,+4M) kq bf16 | [+4M,+8M) vb bf16 | [+8M,+24M) xb bf16 then attnbuf
// d_out (fp32): out [0,8388608) | k [8388608,10485760) | v [10485760,12582912)
//   (bf16 q scratch borrows out's first 16 MiB; overwritten by final gemm)

typedef __bf16 bf16;
typedef __bf16 bf16x8 __attribute__((ext_vector_type(8)));
typedef float  f32x4  __attribute__((ext_vector_type(4)));

#define MFMA16(a, b, c) __builtin_amdgcn_mfma_f32_16x16x32_bf16((a), (b), (c), 0, 0, 0)

// ---------------------------------------------------------------- dtype probe
__global__ __launch_bounds__(256) void detect_convert(
    const unsigned short* __restrict__ probe,   // Wq bits
    const void* __restrict__ qw_raw, const void* __restrict__ kw_raw,
    int* __restrict__ flag, bf16* __restrict__ qwc, bf16* __restrict__ kwc) {
    __shared__ int cnt;
    if (threadIdx.x == 0) cnt = 0;
    __syncthreads();
    int local = 0;
    for (int i = 0; i < 4; ++i) {
        const unsigned short w = probe[(threadIdx.x * 4 + i) * 2];
        const int e = (w >> 7) & 0xFF;
        if (e >= 90 && e <= 140) ++local;
    }
    atomicAdd(&cnt, local);
    __syncthreads();
    const bool isbf16 = cnt >= 700;
    if (threadIdx.x == 0) *flag = isbf16 ? 1 : 0;
    const int t = threadIdx.x;
    if (t < 128)
        qwc[t] = isbf16 ? ((const bf16*)qw_raw)[t] : (bf16)((const float*)qw_raw)[t];
    else
        kwc[t - 128] = isbf16 ? ((const bf16*)kw_raw)[t - 128] : (bf16)((const float*)kw_raw)[t - 128];
}

// ---------------------------------------------------------------- x -> bf16
__global__ __launch_bounds__(256) void convert_x(const void* __restrict__ xv,
                                                 bf16* __restrict__ xb,
                                                 const int* __restrict__ flag) {
    const size_t i8 = ((size_t)blockIdx.x * 256 + threadIdx.x) * 8;
    if (*flag) {
        *(bf16x8*)&xb[i8] = *(const bf16x8*)&((const bf16*)xv)[i8];
    } else {
        const f32x4 a = *(const f32x4*)&((const float*)xv)[i8];
        const f32x4 b = *(const f32x4*)&((const float*)xv)[i8 + 4];
        bf16x8 o;
#pragma unroll
        for (int e = 0; e < 4; ++e) { o[e] = (bf16)a[e]; o[e + 4] = (bf16)b[e]; }
        *(bf16x8*)&xb[i8] = o;
    }
}

// ---------------------------------------------------------------- MFMA GEMM
// A bf16 [M][K] row-major. B (fp32 or bf16 via flag) [K][N] row-major.
// Up to three B/C sets split along bx: [0,ns1) set1, [ns1,ns1+ns2) set2,
// rest set3. 2-phase double-buffered pipeline: loads for tile t+1 issued
// before compute of tile t; ds_write after compute; ONE barrier per K-step.
#define GBM 128
#define GBN 128
#define GBK 64
#define GLD 72

__global__ __launch_bounds__(256) void gemm_nt(
    const bf16* __restrict__ A,
    const void* __restrict__ B1v, const void* __restrict__ B2v, const void* __restrict__ B3v,
    bf16* __restrict__ Cb1, float* __restrict__ Cf1,
    bf16* __restrict__ Cb2, float* __restrict__ Cf2,
    bf16* __restrict__ Cb3, float* __restrict__ Cf3,
    const int* __restrict__ flag, int K,
    int ldb1, int ldb2, int ldb3, int ldc1, int ldc2, int ldc3,
    int ns1, int ns2) {
    __shared__ __align__(16) bf16 As[2][GBM * GLD];
    __shared__ __align__(16) bf16 Bs[2][GBN * GLD];

    // XCD-chunked swizzle (nwg % 8 == 0 for all launches)
    int id = blockIdx.y * gridDim.x + blockIdx.x;
    const int nwg = gridDim.x * gridDim.y;
    id = (id & 7) * (nwg >> 3) + (id >> 3);
    const int bx = id % (int)gridDim.x;
    const int by = id / (int)gridDim.x;

    const void* Bv;
    bf16* Cb;
    float* Cf;
    int n0, ldb, ldc;
    if (bx < ns1) {
        Bv = B1v; Cb = Cb1; Cf = Cf1; n0 = bx * GBN; ldb = ldb1; ldc = ldc1;
    } else if (bx < ns1 + ns2) {
        Bv = B2v; Cb = Cb2; Cf = Cf2; n0 = (bx - ns1) * GBN; ldb = ldb2; ldc = ldc2;
    } else {
        Bv = B3v; Cb = Cb3; Cf = Cf3; n0 = (bx - ns1 - ns2) * GBN; ldb = ldb3; ldc = ldc3;
    }
    const int m0 = by * GBM;

    const bool bBf16 = (*flag) != 0;
    const bf16*  Bb = (const bf16*)Bv;
    const float* Bf = (const float*)Bv;

    const int tid  = threadIdx.x;
    const int wave = tid >> 6;
    const int lane = tid & 63;
    const int l15  = lane & 15;
    const int quad = lane >> 4;
    const int wm = (wave >> 1) * 64;
    const int wn = (wave & 1) * 64;

    // per-thread staging coords (constant across tiles)
    const int ar[4] = { (0 * 256 + tid) >> 3, (1 * 256 + tid) >> 3,
                        (2 * 256 + tid) >> 3, (3 * 256 + tid) >> 3 };
    const int ak = tid & 7;
    // B: chunk p -> (nh, kc): n = nh*64+lane, k-range kc*8..+8
    //    w16 = wave*4+p; nh = w16&1; kc = w16>>1

    f32x4 acc[4][4];
#pragma unroll
    for (int i = 0; i < 4; ++i)
#pragma unroll
        for (int j = 0; j < 4; ++j) acc[i][j] = {0.f, 0.f, 0.f, 0.f};

    bf16x8 aReg[4];
    float  bRegF[4][8];
    bf16   bRegB[4][8];

#define LOAD_TILE(k0)                                                          \
    {                                                                          \
        _Pragma("unroll")                                                      \
        for (int p = 0; p < 4; ++p)                                            \
            aReg[p] = *(const bf16x8*)&A[(size_t)(m0 + ar[p]) * K + (k0) + ak * 8]; \
        if (bBf16) {                                                           \
            _Pragma("unroll")                                                  \
            for (int p = 0; p < 4; ++p) {                                      \
                const int w16 = wave * 4 + p;                                  \
                const int n = (w16 & 1) * 64 + lane, kc = w16 >> 1;            \
                _Pragma("unroll")                                              \
                for (int e = 0; e < 8; ++e)                                    \
                    bRegB[p][e] = Bb[(size_t)((k0) + kc * 8 + e) * ldb + n0 + n]; \
            }                                                                  \
        } else {                                                               \
            _Pragma("unroll")                                                  \
            for (int p = 0; p < 4; ++p) {                                      \
                const int w16 = wave * 4 + p;                                  \
                const int n = (w16 & 1) * 64 + lane, kc = w16 >> 1;            \
                _Pragma("unroll")                                              \
                for (int e = 0; e < 8; ++e)                                    \
                    bRegF[p][e] = Bf[(size_t)((k0) + kc * 8 + e) * ldb + n0 + n]; \
            }                                                                  \
        }                                                                      \
    }

#define WRITE_TILE(buf)                                                        \
    {                                                                          \
        _Pragma("unroll")                                                      \
        for (int p = 0; p < 4; ++p)                                            \
            *(bf16x8*)&As[buf][ar[p] * GLD + ak * 8] = aReg[p];                \
        _Pragma("unroll")                                                      \
        for (int p = 0; p < 4; ++p) {                                          \
            const int w16 = wave * 4 + p;                                      \
            const int n = (w16 & 1) * 64 + lane, kc = w16 >> 1;                \
            bf16x8 bv;                                                         \
            if (bBf16) {                                                       \
                _Pragma("unroll")                                              \
                for (int e = 0; e < 8; ++e) bv[e] = bRegB[p][e];               \
            } else {                                                           \
                _Pragma("unroll")                                              \
                for (int e = 0; e < 8; ++e) bv[e] = (bf16)bRegF[p][e];         \
            }                                                                  \
            *(bf16x8*)&Bs[buf][n * GLD + kc * 8] = bv;                         \
        }                                                                      \
    }

#define COMPUTE_TILE(buf)                                                      \
    {                                                                          \
        _Pragma("unroll")                                                      \
        for (int kk = 0; kk < GBK; kk += 32) {                                 \
            bf16x8 af[4], bfr[4];                                              \
            _Pragma("unroll")                                                  \
            for (int i = 0; i < 4; ++i)                                        \
                af[i] = *(const bf16x8*)&As[buf][(wm + i * 16 + l15) * GLD + kk + quad * 8]; \
            _Pragma("unroll")                                                  \
            for (int j = 0; j < 4; ++j)                                        \
                bfr[j] = *(const bf16x8*)&Bs[buf][(wn + j * 16 + l15) * GLD + kk + quad * 8]; \
            _Pragma("unroll")                                                  \
            for (int i = 0; i < 4; ++i)                                        \
                _Pragma("unroll")                                              \
                for (int j = 0; j < 4; ++j)                                    \
                    acc[i][j] = MFMA16(af[i], bfr[j], acc[i][j]);              \
        }                                                                      \
    }

    const int nt = K >> 6;   // GBK = 64
    LOAD_TILE(0);
    WRITE_TILE(0);
    __syncthreads();
    int cur = 0;
    for (int t = 0; t < nt; ++t) {
        if (t + 1 < nt) LOAD_TILE((t + 1) << 6);
        COMPUTE_TILE(cur);
        if (t + 1 < nt) {
            WRITE_TILE(cur ^ 1);
            __syncthreads();
        }
        cur ^= 1;
    }
#undef LOAD_TILE
#undef WRITE_TILE
#undef COMPUTE_TILE

#pragma unroll
    for (int i = 0; i < 4; ++i)
#pragma unroll
        for (int j = 0; j < 4; ++j)
#pragma unroll
            for (int r = 0; r < 4; ++r) {
                const int row = m0 + wm + i * 16 + quad * 4 + r;
                const int col = n0 + wn + j * 16 + l15;
                const float v = acc[i][j][r];
                if (Cb) Cb[(size_t)row * ldc + col] = (bf16)v;
                if (Cf) Cf[(size_t)row * ldc + col] = v;
            }
}

// ---------------------------------------------------------------- norm + rope
__global__ __launch_bounds__(256) void norm_rope(const bf16* __restrict__ src,
                                                 bf16* __restrict__ dst_bf,
                                                 float* __restrict__ dst_f32,
                                                 const bf16* __restrict__ w,
                                                 const int* __restrict__ positions,
                                                 int H) {
    const int wid  = blockIdx.x * 4 + (threadIdx.x >> 6);
    const int lane = threadIdx.x & 63;
    const int token = wid / H, head = wid % H;
    const bf16* s = src + ((size_t)token * H + head) * 128;
    const float f0 = (float)s[lane], f1 = (float)s[lane + 64];
    float ss = f0 * f0 + f1 * f1;
    for (int off = 32; off >= 1; off >>= 1) ss += __shfl_xor(ss, off);
    const float inv_rms = rsqrtf(ss * (1.0f / 128.0f) + 1e-6f);
    const float n0 = f0 * inv_rms * (float)w[lane];
    const float n1 = f1 * inv_rms * (float)w[lane + 64];
    const float pos = (float)positions[token];
    const float inv_ts = expf((float)lane * (-13.815510557964274f / 64.0f));
    const float ang = pos * inv_ts;
    const float sn = sinf(ang), cs = cosf(ang);
    const float o0 = n0 * cs - n1 * sn;
    const float o1 = n1 * cs + n0 * sn;
    const size_t base = ((size_t)token * H + head) * 128;
    if (dst_bf)  { dst_bf[base + lane] = (bf16)o0;  dst_bf[base + lane + 64] = (bf16)o1; }
    if (dst_f32) { dst_f32[base + lane] = o0;       dst_f32[base + lane + 64] = o1; }
}

// ---------------------------------------------------------------- MFMA flash attention
// 1024 blocks; work id chunked so each XCD handles 4 consecutive heads
// (one KV head, ~1MB, resident in its private L2). Block = 4 waves; wave w
// owns q rows [qt*64 + w*16, +16) of head h. KV tiles of 32 keys in LDS.
__global__ __launch_bounds__(256) void flash_attn(const bf16* __restrict__ Q,
                                                  const bf16* __restrict__ Kg,
                                                  const bf16* __restrict__ Vg,
                                                  bf16* __restrict__ Og) {
    __shared__ __align__(16) bf16 Ks[32 * 128];     // 8 KiB, swizzled
    __shared__ __align__(16) bf16 Vt[128 * 40];     // 10 KiB, V^T padded
    __shared__ __align__(16) bf16 Ps[4][16 * 40];   // 5 KiB, per-wave P

    int id = blockIdx.y * 32 + blockIdx.x;
    id = (id & 7) * 128 + (id >> 3);        // XCD-chunked
    const int h  = id >> 5;                 // head-major within chunk
    const int qt = 31 - (id & 31);          // heavy (long-loop) tiles first
    const int kvh  = h >> 2;
    const int tid  = threadIdx.x;
    const int wave = tid >> 6;
    const int lane = tid & 63;
    const int l15  = lane & 15;
    const int quad = lane >> 4;
    const int q0   = qt * 64;
    const int qw0  = q0 + wave * 16;
    const int myq  = qw0 + l15;
    const float scale = 0.08838834764831845f;  // 1/sqrt(128)

    bf16x8 qf[4];
    {
        const bf16* qrow = Q + ((size_t)myq * 32 + h) * 128;
#pragma unroll
        for (int kc = 0; kc < 4; ++kc)
            qf[kc] = *(const bf16x8*)&qrow[kc * 32 + quad * 8];
    }

    f32x4 oacc[8];
#pragma unroll
    for (int i = 0; i < 8; ++i) oacc[i] = {0.f, 0.f, 0.f, 0.f};
    float m_run = -1e30f, l_run = 0.f;

    const int ksr  = tid & 31;
    const int kscb = tid >> 5;
    const int vr0  = (tid & 15) * 2;
    const int vcb  = tid >> 4;

    char* kbytes = (char*)Ks;
    char* vbytes = (char*)Vt;
    char* pbytes = (char*)&Ps[wave][0];

    const int ntiles = (q0 + 64) >> 5;
    for (int kt = 0; kt < ntiles; ++kt) {
        const int kb = kt * 32;
        {
            const bf16* src = Kg + ((size_t)(kb + ksr) * 8 + kvh) * 128;
            const bf16x8 v0 = *(const bf16x8*)&src[kscb * 8];
            const bf16x8 v1 = *(const bf16x8*)&src[(kscb + 8) * 8];
            const int b0 = (ksr * 256 + kscb * 16) ^ ((ksr & 7) << 4);
            const int b1 = (ksr * 256 + (kscb + 8) * 16) ^ ((ksr & 7) << 4);
            *(bf16x8*)(kbytes + b0) = v0;
            *(bf16x8*)(kbytes + b1) = v1;
        }
        {
            const bf16* s0 = Vg + ((size_t)(kb + vr0) * 8 + kvh) * 128 + vcb * 8;
            const bf16x8 a = *(const bf16x8*)s0;
            const bf16x8 b = *(const bf16x8*)(s0 + 1024);
#pragma unroll
            for (int e = 0; e < 8; ++e) {
                union { bf16 hh[2]; unsigned int u; } pk;
                pk.hh[0] = a[e]; pk.hh[1] = b[e];
                *(unsigned int*)(vbytes + (vcb * 8 + e) * 80 + vr0 * 2) = pk.u;
            }
        }
        __syncthreads();

        f32x4 sacc[2];
        sacc[0] = {0.f, 0.f, 0.f, 0.f};
        sacc[1] = {0.f, 0.f, 0.f, 0.f};
#pragma unroll
        for (int st = 0; st < 2; ++st) {
            const int row = st * 16 + l15;
#pragma unroll
            for (int kc = 0; kc < 4; ++kc) {
                const int bofs = (row * 256 + kc * 64 + quad * 16) ^ ((row & 7) << 4);
                const bf16x8 kf = *(const bf16x8*)(kbytes + bofs);
                sacc[st] = MFMA16(kf, qf[kc], sacc[st]);
            }
        }

        float sv[8];
        float pm = -1e30f;
#pragma unroll
        for (int st = 0; st < 2; ++st)
#pragma unroll
            for (int r = 0; r < 4; ++r) {
                const int key = kb + st * 16 + quad * 4 + r;
                float s = sacc[st][r] * scale;
                if (key > myq) s = -1e30f;
                sv[st * 4 + r] = s;
                pm = fmaxf(pm, s);
            }
        pm = fmaxf(pm, __shfl_xor(pm, 16));
        pm = fmaxf(pm, __shfl_xor(pm, 32));
        const float m_new = fmaxf(m_run, pm);
        const float corr = __expf(m_run - m_new);
        float ps = 0.f;
        bf16 pb[8];
#pragma unroll
        for (int i = 0; i < 8; ++i) {
            const float p = __expf(sv[i] - m_new);
            ps += p;
            pb[i] = (bf16)p;
        }
        ps += __shfl_xor(ps, 16);
        ps += __shfl_xor(ps, 32);
        l_run = l_run * corr + ps;
        m_run = m_new;

#pragma unroll
        for (int st = 0; st < 2; ++st)
#pragma unroll
            for (int r = 0; r < 4; ++r)
                *(bf16*)(pbytes + l15 * 80 + (st * 16 + quad * 4 + r) * 2) = pb[st * 4 + r];

        float corrq[4];
#pragma unroll
        for (int r = 0; r < 4; ++r) corrq[r] = __shfl(corr, quad * 4 + r);
#pragma unroll
        for (int nt = 0; nt < 8; ++nt)
#pragma unroll
            for (int r = 0; r < 4; ++r) oacc[nt][r] *= corrq[r];

        const bf16x8 pf = *(const bf16x8*)(pbytes + l15 * 80 + quad * 16);
#pragma unroll
        for (int nt = 0; nt < 8; ++nt) {
            const bf16x8 vf = *(const bf16x8*)(vbytes + (nt * 16 + l15) * 80 + quad * 16);
            oacc[nt] = MFMA16(pf, vf, oacc[nt]);
        }
        __syncthreads();
    }

    const float rinv = 1.0f / l_run;
    float linv[4];
#pragma unroll
    for (int r = 0; r < 4; ++r) linv[r] = __shfl(rinv, quad * 4 + r);
#pragma unroll
    for (int nt = 0; nt < 8; ++nt)
#pragma unroll
        for (int r = 0; r < 4; ++r) {
            const int row = qw0 + quad * 4 + r;
            Og[((size_t)row * 32 + h) * 128 + nt * 16 + l15] = (bf16)(oacc[nt][r] * linv[r]);
        }
}

// ---------------------------------------------------------------- launch
extern "C" void kernel_launch(void* const* d_in, const int* in_sizes, int n_in,
                              void* d_out, int out_size, void* d_ws, size_t ws_size,
                              hipStream_t stream) {
    const void* x  = d_in[0];   // [2048][4096]  fp32 or bf16 (auto-detected)
    const void* Wq = d_in[1];   // [4096][4096]
    const void* Wk = d_in[2];   // [4096][1024]
    const void* Wv = d_in[3];   // [4096][1024]
    const void* Wo = d_in[4];   // [4096][4096]
    const void* qw = d_in[5];   // [128]
    const void* kw = d_in[6];   // [128]
    const int* positions = (const int*)d_in[8];

    char* ws = (char*)d_ws;
    int*  flag    = (int*)ws;
    bf16* qwc     = (bf16*)(ws + 64);
    bf16* kwc     = (bf16*)(ws + 64 + 256);
    bf16* kq      = (bf16*)(ws + 4096);                 // [2048][8][128] bf16
    bf16* vb      = (bf16*)(ws + 4096 + 4194304);       // [2048][8][128] bf16
    bf16* xb      = (bf16*)(ws + 4096 + 8388608);       // [2048][4096] bf16 (pre-flash)
    bf16* attnbuf = (bf16*)(ws + 4096 + 8388608);       // [2048][32][128] bf16 (post-flash)

    float* outf = (float*)d_out;           // [2048][4096] fp32
    float* Kof  = outf + 8388608;          // [2048][8][128] fp32
    float* Vof  = outf + 10485760;         // [2048][8][128] fp32
    bf16*  qb   = (bf16*)d_out;            // bf16 q scratch in out's first 16 MiB

    detect_convert<<<1, 256, 0, stream>>>((const unsigned short*)Wq, qw, kw, flag, qwc, kwc);
    convert_x<<<4096, 256, 0, stream>>>(x, xb, flag);

    // All three projections in ONE launch: bx [0,32) Wq -> qb, [32,40) Wk -> kq,
    // [40,48) Wv -> vb + Vof. 768 blocks.
    gemm_nt<<<dim3(48, 16), 256, 0, stream>>>(
        xb, Wq, Wk, Wv,
        qb, nullptr, kq, nullptr, vb, Vof,
        flag, 4096,
        4096, 1024, 1024, 4096, 1024, 1024,
        32, 8);

    // Norm+RoPE. q in-place bf16; k in-place bf16 (attn input) + fp32 (output 1).
    norm_rope<<<16384, 256, 0, stream>>>(qb, qb, nullptr, qwc, positions, 32);
    norm_rope<<<4096, 256, 0, stream>>>(kq, kq, Kof, kwc, positions, 8);

    // Flash attention (MFMA) -> attnbuf bf16 [2048][32][128] (overwrites xb).
    flash_attn<<<dim3(32, 32), 256, 0, stream>>>(qb, kq, vb, attnbuf);

    // Output projection -> fp32 out (overwrites qb scratch after last use).
    gemm_nt<<<dim3(32, 16), 256, 0, stream>>>(
        attnbuf, Wo, Wo, Wo,
        nullptr, outf, nullptr, nullptr, nullptr, nullptr,
        flag, 4096,
        4096, 4096, 4096, 4096, 4096, 4096,
        32, 0);
}